// Round 3
// baseline (579.805 us; speedup 1.0000x reference)
//
#include <hip/hip_runtime.h>

#define NN 4096
#define IN_F 256
#define OUT_F 64
#define K_CH 4
#define ALPHA 0.2f
#define ROWS1 32       // rows per k1 chunk
#define IC1 128        // NN / ROWS1 chunks per channel
#define BSTRIDE 264    // LDS B-slab row stride (bf16 elems): even 8/bank, 16B-aligned

typedef __bf16 bf16;
typedef __attribute__((ext_vector_type(8))) __bf16 bf16x8;
typedef __attribute__((ext_vector_type(4))) __bf16 bf16x4;
typedef __attribute__((ext_vector_type(4))) float f32x4;

// ---------------- k0: Wh = h@W (fp32) ; Wh1 = Wh@a[:64] ; Wh2 = Wh@a[64:]
__global__ __launch_bounds__(256) void k0_wh(const float* __restrict__ h,
                                             const float* __restrict__ W,
                                             const float* __restrict__ a,
                                             float* __restrict__ Wh,
                                             float* __restrict__ Wh1,
                                             float* __restrict__ Wh2) {
    int tid = threadIdx.x;
    int wave = tid >> 6, lane = tid & 63;
    int i = blockIdx.x * 4 + wave;
    const float* hrow = h + (size_t)i * IN_F;
    float acc = 0.f;
    #pragma unroll 8
    for (int c = 0; c < IN_F; ++c)
        acc += hrow[c] * W[c * OUT_F + lane];
    Wh[(size_t)i * OUT_F + lane] = acc;
    float v1 = acc * a[lane];
    float v2 = acc * a[OUT_F + lane];
    #pragma unroll
    for (int o = 32; o > 0; o >>= 1) {
        v1 += __shfl_xor(v1, o, 64);
        v2 += __shfl_xor(v2, o, 64);
    }
    if (lane == 0) { Wh1[i] = v1; Wh2[i] = v2; }
}

// ---------------- k0T: WhT[f][j] = (bf16)Wh[j][f]   (for MFMA B-fragments)
__global__ __launch_bounds__(256) void k0_transpose(const float* __restrict__ Wh,
                                                    bf16* __restrict__ WhT) {
    __shared__ float lds[OUT_F * 65];
    int tid = threadIdx.x;
    int i0 = blockIdx.x * 64;
    int f = tid & 63;
    int r0 = tid >> 6;
    #pragma unroll
    for (int s = 0; s < 16; ++s) {
        int r = r0 * 16 + s;
        lds[f * 65 + r] = Wh[(size_t)(i0 + r) * OUT_F + f];
    }
    __syncthreads();
    int f2 = tid >> 2;
    int c0 = (tid & 3) * 16;
    bf16x8 v0, v1;
    #pragma unroll
    for (int s = 0; s < 8; ++s) {
        v0[s] = (bf16)lds[f2 * 65 + c0 + s];
        v1[s] = (bf16)lds[f2 * 65 + c0 + 8 + s];
    }
    *(bf16x8*)&WhT[(size_t)f2 * NN + i0 + c0] = v0;
    *(bf16x8*)&WhT[(size_t)f2 * NN + i0 + c0 + 8] = v1;
}

// ---------------- k1: pass 1 over edge — colsums of bf16-rounded p ONLY.
// No p materialization (pass 2 recomputes p bit-identically from edge).
__global__ __launch_bounds__(256) void k1_colsum(const float* __restrict__ edge,
                                                 const float* __restrict__ Wh1,
                                                 const float* __restrict__ Wh2,
                                                 float* __restrict__ partial) {
    int tid = threadIdx.x;
    int kch = blockIdx.z;
    int j0 = blockIdx.y * 1024 + tid * 4;
    int ic = blockIdx.x;
    int ibase = ic * ROWS1;
    f32x4 w2 = *(const f32x4*)&Wh2[j0];
    f32x4 w1v[ROWS1 / 4];
    #pragma unroll
    for (int t = 0; t < ROWS1 / 4; ++t)
        w1v[t] = *(const f32x4*)&Wh1[ibase + t * 4];
    f32x4 s = {0.f, 0.f, 0.f, 0.f};
    const float* base = edge + ((size_t)kch * NN + ibase) * NN + j0;
    f32x4 r[8];
    #pragma unroll
    for (int t = 0; t < 8; ++t)
        r[t] = *(const f32x4*)(base + (size_t)t * NN);
    #pragma unroll
    for (int ii = 0; ii < ROWS1; ++ii) {
        f32x4 e = r[ii & 7];
        if (ii + 8 < ROWS1)                       // compile-time (full unroll)
            r[ii & 7] = *(const f32x4*)(base + (size_t)(ii + 8) * NN);
        float wh1 = w1v[ii >> 2][ii & 3];
        #pragma unroll
        for (int c = 0; c < 4; ++c) {
            float xv = wh1 + w2[c];
            float lk = xv > 0.f ? xv : ALPHA * xv;
            float val = e[c] > 0.f ? __expf(lk * e[c]) : 0.f;
            bf16 vb = (bf16)val;                  // sum the ROUNDED value
            s[c] += (float)vb;                    // -> softmax consistent w/ pass 2
        }
    }
    *(f32x4*)(partial + ((size_t)kch * IC1 + ic) * NN + j0) = s;
}

// ---------------- k1b: s_inv[k][j] = 1/colsum, AND pre-scale the GEMM B-operand:
// WhTs[k][f][j] = bf16( WhT[f][j] * s_inv[k][j] ) — normalization leaves the GEMM.
__global__ __launch_bounds__(256) void k1_reduce(const float* __restrict__ partial,
                                                 const bf16* __restrict__ WhT,
                                                 float* __restrict__ s_inv,
                                                 bf16* __restrict__ WhTs) {
    __shared__ float red[256];
    __shared__ float inv_l[64];
    int tid = threadIdx.x;
    int kch = blockIdx.y;
    int jl = tid & 63, g = tid >> 6;
    int jbase = blockIdx.x * 64;
    int j = jbase + jl;
    const float* pb = partial + (size_t)kch * IC1 * NN;
    float s = 0.f;
    #pragma unroll 8
    for (int t = 0; t < IC1 / 4; ++t)
        s += pb[(size_t)(g * (IC1 / 4) + t) * NN + j];
    red[tid] = s;
    __syncthreads();
    if (tid < 64) {
        float tot = red[tid] + red[tid + 64] + red[tid + 128] + red[tid + 192];
        float iv = tot > 0.f ? 1.f / tot : 0.f;
        s_inv[kch * NN + j] = iv;
        inv_l[tid] = iv;
    }
    __syncthreads();
    int f = tid >> 2;
    int c0 = (tid & 3) * 16;
    bf16x8 a0 = *(const bf16x8*)&WhT[(size_t)f * NN + jbase + c0];
    bf16x8 a1 = *(const bf16x8*)&WhT[(size_t)f * NN + jbase + c0 + 8];
    bf16x8 o0, o1;
    #pragma unroll
    for (int s2 = 0; s2 < 8; ++s2) {
        o0[s2] = (bf16)((float)a0[s2] * inv_l[c0 + s2]);
        o1[s2] = (bf16)((float)a1[s2] * inv_l[c0 + 8 + s2]);
    }
    bf16* wb = WhTs + ((size_t)kch * OUT_F + f) * NN + jbase + c0;
    *(bf16x8*)wb = o0;
    *(bf16x8*)(wb + 8) = o1;
}

// ---------------- k2: pass 2 over edge. Recomputes p (bit-identical to k1's),
// writes att = p*inv directly (plain stores), and MFMAs p against the
// pre-scaled WhTs slab -> per-jq hp partials. Grid (64 itile, 4 jq, 4 kch)
// = 1024 blocks -> 4 blocks/CU (34 KB LDS), 16 waves/CU.
__global__ __launch_bounds__(256, 4) void k2_fused(const float* __restrict__ edge,
                                                   const float* __restrict__ Wh1,
                                                   const float* __restrict__ Wh2,
                                                   const float* __restrict__ s_inv,
                                                   const bf16* __restrict__ WhTs,
                                                   float* __restrict__ att_out,
                                                   float* __restrict__ hp_part) {
    __shared__ bf16 ldsB[OUT_F * BSTRIDE];
    int tid = threadIdx.x;
    int itile = blockIdx.x;
    int jq = blockIdx.y;
    int kch = blockIdx.z;
    int wave = tid >> 6, lane = tid & 63;
    int n16 = lane & 15, quad = lane >> 4;
    int i_row = itile * 64 + wave * 16 + n16;
    int jbase = jq * 1024;
    const float* erow = edge + ((size_t)kch * NN + i_row) * NN + jbase + quad * 8;
    float* arow = att_out + ((size_t)kch * NN + i_row) * NN + jbase + quad * 8;
    const float* w2p = Wh2 + jbase + quad * 8;
    const float* ivp = s_inv + kch * NN + jbase + quad * 8;
    float wh1 = Wh1[i_row];
    f32x4 acc[4] = {};
    // prefetch ring: depth 4 g-steps, 2 x f32x4 per step (8 edge floats/lane)
    f32x4 pf0[4], pf1[4];
    #pragma unroll
    for (int t = 0; t < 4; ++t) {
        pf0[t] = *(const f32x4*)(erow + t * 32);
        pf1[t] = *(const f32x4*)(erow + t * 32 + 4);
    }
    int f = tid >> 2, part = (tid & 3) * 64;
    const bf16* wsrc = WhTs + ((size_t)kch * OUT_F + f) * NN + jbase + part;
    #pragma unroll
    for (int slab = 0; slab < 4; ++slab) {
        __syncthreads();
        #pragma unroll
        for (int u = 0; u < 8; ++u) {
            bf16x8 v = *(const bf16x8*)(wsrc + slab * 256 + u * 8);
            *(bf16x8*)&ldsB[f * BSTRIDE + part + u * 8] = v;
        }
        __syncthreads();
        #pragma unroll
        for (int t = 0; t < 8; ++t) {
            int g = slab * 8 + t;                  // compile-time (both unrolled)
            int cur = g & 3;
            f32x4 e0 = pf0[cur], e1 = pf1[cur];
            if (g + 4 < 32) {
                pf0[cur] = *(const f32x4*)(erow + (g + 4) * 32);
                pf1[cur] = *(const f32x4*)(erow + (g + 4) * 32 + 4);
            }
            f32x4 w2a = *(const f32x4*)(w2p + g * 32);
            f32x4 w2b = *(const f32x4*)(w2p + g * 32 + 4);
            f32x4 iva = *(const f32x4*)(ivp + g * 32);
            f32x4 ivb = *(const f32x4*)(ivp + g * 32 + 4);
            bf16x8 afrag;
            f32x4 av0, av1;
            #pragma unroll
            for (int c = 0; c < 8; ++c) {
                float e  = c < 4 ? e0[c]  : e1[c - 4];
                float wv = c < 4 ? w2a[c] : w2b[c - 4];
                float iv = c < 4 ? iva[c] : ivb[c - 4];
                float xv = wh1 + wv;
                float lk = xv > 0.f ? xv : ALPHA * xv;
                float val = e > 0.f ? __expf(lk * e) : 0.f;
                bf16 vb = (bf16)val;               // same rounding as k1_colsum
                afrag[c] = vb;
                float attv = (float)vb * iv;
                if (c < 4) av0[c] = attv; else av1[c - 4] = attv;
            }
            *(f32x4*)(arow + g * 32) = av0;
            *(f32x4*)(arow + g * 32 + 4) = av1;
            int jl = t * 32 + quad * 8;
            #pragma unroll
            for (int ft = 0; ft < 4; ++ft) {
                bf16x8 bfrag = *(const bf16x8*)&ldsB[(ft * 16 + n16) * BSTRIDE + jl];
                acc[ft] = __builtin_amdgcn_mfma_f32_16x16x32_bf16(afrag, bfrag, acc[ft], 0, 0, 0);
            }
        }
    }
    // epilogue: hp_part[kch][jq][i][f].  C/D layout: col=lane&15, row=quad*4+reg.
    float* hb = hp_part + (((size_t)kch * 4 + jq) * NN) * OUT_F;
    #pragma unroll
    for (int ft = 0; ft < 4; ++ft) {
        #pragma unroll
        for (int r = 0; r < 4; ++r) {
            int i_g = itile * 64 + wave * 16 + quad * 4 + r;
            hb[(size_t)i_g * OUT_F + ft * 16 + n16] = acc[ft][r];
        }
    }
}

// ---------------- k3: out = elu( sum_jq hp_part ).  20 MB of traffic, ~3 us.
__global__ __launch_bounds__(256) void k3_elu(const float* __restrict__ hp_part,
                                              float* __restrict__ out) {
    int i = blockIdx.x;
    int tid = threadIdx.x;          // kch*64 + f
    int kch = tid >> 6, f = tid & 63;
    float s = 0.f;
    #pragma unroll
    for (int jq = 0; jq < 4; ++jq)
        s += hp_part[(((size_t)kch * 4 + jq) * NN + i) * OUT_F + f];
    out[(size_t)i * (K_CH * OUT_F) + tid] = s > 0.f ? s : __expf(s) - 1.f;
}

extern "C" void kernel_launch(void* const* d_in, const int* in_sizes, int n_in,
                              void* d_out, int out_size, void* d_ws, size_t ws_size,
                              hipStream_t stream) {
    (void)out_size; (void)ws_size;
    const float *h = nullptr, *edge = nullptr, *W = nullptr, *a = nullptr;
    for (int i = 0; i < n_in; ++i) {
        int sz = in_sizes[i];
        if (sz == NN * IN_F)               h    = (const float*)d_in[i];
        else if (sz == K_CH * NN * NN)     edge = (const float*)d_in[i];
        else if (sz == IN_F * OUT_F)       W    = (const float*)d_in[i];
        else if (sz == 2 * OUT_F)          a    = (const float*)d_in[i];
    }

    char* ws = (char*)d_ws;
    size_t off = 0;
    float* Wh      = (float*)(ws + off); off += (size_t)NN * OUT_F * 4;               // 1 MB
    float* Wh1     = (float*)(ws + off); off += NN * 4;                               // 16 KB
    float* Wh2     = (float*)(ws + off); off += NN * 4;                               // 16 KB
    float* s_inv   = (float*)(ws + off); off += (size_t)K_CH * NN * 4;                // 64 KB
    bf16*  WhT     = (bf16*) (ws + off); off += (size_t)OUT_F * NN * 2;               // 512 KB
    bf16*  WhTs    = (bf16*) (ws + off); off += (size_t)K_CH * OUT_F * NN * 2;        // 2 MB
    float* partial = (float*)(ws + off); off += (size_t)K_CH * IC1 * NN * 4;          // 8.4 MB
    float* hp_part = (float*)(ws + off); off += (size_t)K_CH * 4 * NN * OUT_F * 4;    // 16.8 MB

    float* out_h   = (float*)d_out;
    float* att_out = out_h + (size_t)NN * (K_CH * OUT_F);

    k0_wh<<<dim3(NN / 4), 256, 0, stream>>>(h, W, a, Wh, Wh1, Wh2);
    k0_transpose<<<dim3(NN / 64), 256, 0, stream>>>(Wh, WhT);
    k1_colsum<<<dim3(IC1, 4, K_CH), 256, 0, stream>>>(edge, Wh1, Wh2, partial);
    k1_reduce<<<dim3(NN / 64, K_CH), 256, 0, stream>>>(partial, WhT, s_inv, WhTs);
    k2_fused<<<dim3(64, 4, K_CH), 256, 0, stream>>>(edge, Wh1, Wh2, s_inv, WhTs,
                                                    att_out, hp_part);
    k3_elu<<<dim3(NN), 256, 0, stream>>>(hp_part, out_h);
}

// Round 4
// 555.794 us; speedup vs baseline: 1.0432x; 1.0432x over previous
//
#include <hip/hip_runtime.h>

#define NN 4096
#define IN_F 256
#define OUT_F 64
#define K_CH 4
#define ALPHA 0.2f
#define ROWS1 32       // rows per k1 chunk
#define IC1 128        // NN / ROWS1 chunks per channel
#define BSTRIDE 264    // LDS B-slab row stride (bf16 elems): even 8/bank, 16B-aligned

typedef __bf16 bf16;
typedef __attribute__((ext_vector_type(8))) __bf16 bf16x8;
typedef __attribute__((ext_vector_type(4))) __bf16 bf16x4;
typedef __attribute__((ext_vector_type(4))) float f32x4;

// ---------------- k0: Wh = h@W (fp32) ; Wh1 = Wh@a[:64] ; Wh2 = Wh@a[64:]
__global__ __launch_bounds__(256) void k0_wh(const float* __restrict__ h,
                                             const float* __restrict__ W,
                                             const float* __restrict__ a,
                                             float* __restrict__ Wh,
                                             float* __restrict__ Wh1,
                                             float* __restrict__ Wh2) {
    int tid = threadIdx.x;
    int wave = tid >> 6, lane = tid & 63;
    int i = blockIdx.x * 4 + wave;
    const float* hrow = h + (size_t)i * IN_F;
    float acc = 0.f;
    #pragma unroll 8
    for (int c = 0; c < IN_F; ++c)
        acc += hrow[c] * W[c * OUT_F + lane];
    Wh[(size_t)i * OUT_F + lane] = acc;
    float v1 = acc * a[lane];
    float v2 = acc * a[OUT_F + lane];
    #pragma unroll
    for (int o = 32; o > 0; o >>= 1) {
        v1 += __shfl_xor(v1, o, 64);
        v2 += __shfl_xor(v2, o, 64);
    }
    if (lane == 0) { Wh1[i] = v1; Wh2[i] = v2; }
}

// ---------------- k0T: WhT[f][j] = (bf16)Wh[j][f]   (for MFMA B-fragments)
__global__ __launch_bounds__(256) void k0_transpose(const float* __restrict__ Wh,
                                                    bf16* __restrict__ WhT) {
    __shared__ float lds[OUT_F * 65];
    int tid = threadIdx.x;
    int i0 = blockIdx.x * 64;
    int f = tid & 63;
    int r0 = tid >> 6;
    #pragma unroll
    for (int s = 0; s < 16; ++s) {
        int r = r0 * 16 + s;
        lds[f * 65 + r] = Wh[(size_t)(i0 + r) * OUT_F + f];
    }
    __syncthreads();
    int f2 = tid >> 2;
    int c0 = (tid & 3) * 16;
    bf16x8 v0, v1;
    #pragma unroll
    for (int s = 0; s < 8; ++s) {
        v0[s] = (bf16)lds[f2 * 65 + c0 + s];
        v1[s] = (bf16)lds[f2 * 65 + c0 + 8 + s];
    }
    *(bf16x8*)&WhT[(size_t)f2 * NN + i0 + c0] = v0;
    *(bf16x8*)&WhT[(size_t)f2 * NN + i0 + c0 + 8] = v1;
}

// ---------------- k1: the ONLY edge reader. NT loads keep the 268 MB edge
// stream OUT of L3 so the freshly written 134 MB p stays L3-resident for k2.
// p[k][i][j] = bf16(masked exp); partial[k][ic][j] = chunk col sums (over i).
__global__ __launch_bounds__(256) void k1_colsum(const float* __restrict__ edge,
                                                 const float* __restrict__ Wh1,
                                                 const float* __restrict__ Wh2,
                                                 bf16* __restrict__ p_buf,
                                                 float* __restrict__ partial) {
    int tid = threadIdx.x;
    int kch = blockIdx.z;
    int j0 = blockIdx.y * 1024 + tid * 4;
    int ic = blockIdx.x;
    int ibase = ic * ROWS1;
    f32x4 w2 = *(const f32x4*)&Wh2[j0];
    f32x4 w1v[ROWS1 / 4];
    #pragma unroll
    for (int t = 0; t < ROWS1 / 4; ++t)
        w1v[t] = *(const f32x4*)&Wh1[ibase + t * 4];
    f32x4 s = {0.f, 0.f, 0.f, 0.f};
    const float* base = edge + ((size_t)kch * NN + ibase) * NN + j0;
    bf16* pbase = p_buf + ((size_t)kch * NN + ibase) * NN + j0;
    f32x4 r[8];
    #pragma unroll
    for (int t = 0; t < 8; ++t)
        r[t] = __builtin_nontemporal_load((const f32x4*)(base + (size_t)t * NN));
    #pragma unroll
    for (int ii = 0; ii < ROWS1; ++ii) {
        f32x4 e = r[ii & 7];
        if (ii + 8 < ROWS1)                       // compile-time (full unroll)
            r[ii & 7] = __builtin_nontemporal_load(
                            (const f32x4*)(base + (size_t)(ii + 8) * NN));
        float wh1 = w1v[ii >> 2][ii & 3];
        bf16x4 pv;
        #pragma unroll
        for (int c = 0; c < 4; ++c) {
            float xv = wh1 + w2[c];
            float lk = xv > 0.f ? xv : ALPHA * xv;
            float val = e[c] > 0.f ? __expf(lk * e[c]) : 0.f;
            bf16 vb = (bf16)val;
            pv[c] = vb;
            s[c] += (float)vb;     // sum the ROUNDED value -> consistent softmax
        }
        *(bf16x4*)(pbase + (size_t)ii * NN) = pv;   // plain store: want p in L3
    }
    *(f32x4*)(partial + ((size_t)kch * IC1 + ic) * NN + j0) = s;
}

// ---------------- k1b: s_inv[k][j] = 1/colsum, AND pre-scale the GEMM B-operand:
// WhTs[k][f][j] = bf16( WhT[f][j] * s_inv[k][j] ) — normalization leaves the GEMM.
__global__ __launch_bounds__(256) void k1_reduce(const float* __restrict__ partial,
                                                 const bf16* __restrict__ WhT,
                                                 float* __restrict__ s_inv,
                                                 bf16* __restrict__ WhTs) {
    __shared__ float red[256];
    __shared__ float inv_l[64];
    int tid = threadIdx.x;
    int kch = blockIdx.y;
    int jl = tid & 63, g = tid >> 6;
    int jbase = blockIdx.x * 64;
    int j = jbase + jl;
    const float* pb = partial + (size_t)kch * IC1 * NN;
    float s = 0.f;
    #pragma unroll 8
    for (int t = 0; t < IC1 / 4; ++t)
        s += pb[(size_t)(g * (IC1 / 4) + t) * NN + j];
    red[tid] = s;
    __syncthreads();
    if (tid < 64) {
        float tot = red[tid] + red[tid + 64] + red[tid + 128] + red[tid + 192];
        float iv = tot > 0.f ? 1.f / tot : 0.f;
        s_inv[kch * NN + j] = iv;
        inv_l[tid] = iv;
    }
    __syncthreads();
    int f = tid >> 2;
    int c0 = (tid & 3) * 16;
    bf16x8 a0 = *(const bf16x8*)&WhT[(size_t)f * NN + jbase + c0];
    bf16x8 a1 = *(const bf16x8*)&WhT[(size_t)f * NN + jbase + c0 + 8];
    bf16x8 o0, o1;
    #pragma unroll
    for (int s2 = 0; s2 < 8; ++s2) {
        o0[s2] = (bf16)((float)a0[s2] * inv_l[c0 + s2]);
        o1[s2] = (bf16)((float)a1[s2] * inv_l[c0 + 8 + s2]);
    }
    bf16* wb = WhTs + ((size_t)kch * OUT_F + f) * NN + jbase + c0;
    *(bf16x8*)wb = o0;
    *(bf16x8*)(wb + 8) = o1;
}

// ---------------- k2: single reader of p (L3-hot). Per 16B p load it BOTH
// writes att = p*inv AND feeds the MFMA A-fragment (raw bf16 p; inv is folded
// into WhTs). Grid (64 itile, 4 jq, 4 kch) = 1024 blocks -> 4 blocks/CU
// (34 KB LDS), 16 waves/CU — 4x R1's k2_mfma occupancy, half its p traffic.
__global__ __launch_bounds__(256, 4) void k2_fused(const bf16* __restrict__ p_buf,
                                                   const float* __restrict__ s_inv,
                                                   const bf16* __restrict__ WhTs,
                                                   float* __restrict__ att_out,
                                                   float* __restrict__ hp_part) {
    __shared__ bf16 ldsB[OUT_F * BSTRIDE];
    int tid = threadIdx.x;
    int itile = blockIdx.x;
    int jq = blockIdx.y;
    int kch = blockIdx.z;
    int wave = tid >> 6, lane = tid & 63;
    int n16 = lane & 15, quad = lane >> 4;
    int i_row = itile * 64 + wave * 16 + n16;
    int jbase = jq * 1024;
    const bf16* prow = p_buf + ((size_t)kch * NN + i_row) * NN + jbase + quad * 8;
    float* arow = att_out + ((size_t)kch * NN + i_row) * NN + jbase + quad * 8;
    const float* ivp = s_inv + kch * NN + jbase + quad * 8;
    f32x4 acc[4] = {};
    // depth-8 prefetch ring over the 32 g-steps (32 j per step)
    bf16x8 pf[8];
    #pragma unroll
    for (int t = 0; t < 8; ++t)
        pf[t] = *(const bf16x8*)(prow + t * 32);
    int f = tid >> 2, part = (tid & 3) * 64;
    const bf16* wsrc = WhTs + ((size_t)kch * OUT_F + f) * NN + jbase + part;
    #pragma unroll
    for (int slab = 0; slab < 4; ++slab) {
        __syncthreads();
        #pragma unroll
        for (int u = 0; u < 8; ++u) {
            bf16x8 v = *(const bf16x8*)(wsrc + slab * 256 + u * 8);
            *(bf16x8*)&ldsB[f * BSTRIDE + part + u * 8] = v;
        }
        __syncthreads();
        #pragma unroll
        for (int t = 0; t < 8; ++t) {
            int g = slab * 8 + t;                  // compile-time (both unrolled)
            bf16x8 pv = pf[g & 7];
            if (g + 8 < 32)
                pf[g & 7] = *(const bf16x8*)(prow + (g + 8) * 32);
            f32x4 iva = *(const f32x4*)(ivp + g * 32);
            f32x4 ivb = *(const f32x4*)(ivp + g * 32 + 4);
            f32x4 av0, av1;
            #pragma unroll
            for (int c = 0; c < 4; ++c) {
                av0[c] = (float)pv[c] * iva[c];
                av1[c] = (float)pv[c + 4] * ivb[c];
            }
            *(f32x4*)(arow + g * 32) = av0;
            *(f32x4*)(arow + g * 32 + 4) = av1;
            int jl = t * 32 + quad * 8;
            #pragma unroll
            for (int ft = 0; ft < 4; ++ft) {
                bf16x8 bfrag = *(const bf16x8*)&ldsB[(ft * 16 + n16) * BSTRIDE + jl];
                acc[ft] = __builtin_amdgcn_mfma_f32_16x16x32_bf16(pv, bfrag, acc[ft], 0, 0, 0);
            }
        }
    }
    // epilogue: hp_part[kch][jq][i][f].  C/D layout: col=lane&15, row=quad*4+reg.
    float* hb = hp_part + (((size_t)kch * 4 + jq) * NN) * OUT_F;
    #pragma unroll
    for (int ft = 0; ft < 4; ++ft) {
        #pragma unroll
        for (int r = 0; r < 4; ++r) {
            int i_g = itile * 64 + wave * 16 + quad * 4 + r;
            hb[(size_t)i_g * OUT_F + ft * 16 + n16] = acc[ft][r];
        }
    }
}

// ---------------- k3: out = elu( sum_jq hp_part ).  20 MB of traffic, ~3 us.
__global__ __launch_bounds__(256) void k3_elu(const float* __restrict__ hp_part,
                                              float* __restrict__ out) {
    int i = blockIdx.x;
    int tid = threadIdx.x;          // kch*64 + f
    int kch = tid >> 6, f = tid & 63;
    float s = 0.f;
    #pragma unroll
    for (int jq = 0; jq < 4; ++jq)
        s += hp_part[(((size_t)kch * 4 + jq) * NN + i) * OUT_F + f];
    out[(size_t)i * (K_CH * OUT_F) + tid] = s > 0.f ? s : __expf(s) - 1.f;
}

extern "C" void kernel_launch(void* const* d_in, const int* in_sizes, int n_in,
                              void* d_out, int out_size, void* d_ws, size_t ws_size,
                              hipStream_t stream) {
    (void)out_size; (void)ws_size;
    const float *h = nullptr, *edge = nullptr, *W = nullptr, *a = nullptr;
    for (int i = 0; i < n_in; ++i) {
        int sz = in_sizes[i];
        if (sz == NN * IN_F)               h    = (const float*)d_in[i];
        else if (sz == K_CH * NN * NN)     edge = (const float*)d_in[i];
        else if (sz == IN_F * OUT_F)       W    = (const float*)d_in[i];
        else if (sz == 2 * OUT_F)          a    = (const float*)d_in[i];
    }

    char* ws = (char*)d_ws;
    size_t off = 0;
    float* Wh      = (float*)(ws + off); off += (size_t)NN * OUT_F * 4;               // 1 MB
    float* Wh1     = (float*)(ws + off); off += NN * 4;                               // 16 KB
    float* Wh2     = (float*)(ws + off); off += NN * 4;                               // 16 KB
    float* s_inv   = (float*)(ws + off); off += (size_t)K_CH * NN * 4;                // 64 KB
    bf16*  WhT     = (bf16*) (ws + off); off += (size_t)OUT_F * NN * 2;               // 512 KB
    bf16*  WhTs    = (bf16*) (ws + off); off += (size_t)K_CH * OUT_F * NN * 2;        // 2 MB
    float* partial = (float*)(ws + off); off += (size_t)K_CH * IC1 * NN * 4;          // 8.4 MB
    float* hp_part = (float*)(ws + off); off += (size_t)K_CH * 4 * NN * OUT_F * 4;    // 16.8 MB
    bf16*  p_buf   = (bf16*) (ws + off); off += (size_t)K_CH * NN * NN * 2;           // 134 MB

    float* out_h   = (float*)d_out;
    float* att_out = out_h + (size_t)NN * (K_CH * OUT_F);

    k0_wh<<<dim3(NN / 4), 256, 0, stream>>>(h, W, a, Wh, Wh1, Wh2);
    k0_transpose<<<dim3(NN / 64), 256, 0, stream>>>(Wh, WhT);
    k1_colsum<<<dim3(IC1, 4, K_CH), 256, 0, stream>>>(edge, Wh1, Wh2, p_buf, partial);
    k1_reduce<<<dim3(NN / 64, K_CH), 256, 0, stream>>>(partial, WhT, s_inv, WhTs);
    k2_fused<<<dim3(64, 4, K_CH), 256, 0, stream>>>(p_buf, s_inv, WhTs, att_out, hp_part);
    k3_elu<<<dim3(NN), 256, 0, stream>>>(hp_part, out_h);
}